// Round 5
// baseline (1462.069 us; speedup 1.0000x reference)
//
#include <hip/hip_runtime.h>

static constexpr int NROWS = 65536;
static constexpr int D_IN  = 768;
static constexpr int D_EMB = 128;
static constexpr long LOSS_OFF  = (long)NROWS * D_EMB;   // 8388608
static constexpr long CODES_OFF = LOSS_OFF + 1;

__device__ __forceinline__ float dot4(float4 a, float4 b){
  return fmaf(a.x,b.x, fmaf(a.y,b.y, fmaf(a.z,b.z, a.w*b.w)));
}

// ---------------------------------------------------------------------------
// Tiled fp32 GEMM: C[M,N] = A[M,K] * B[N,K]^T + bias (optional relu).
// BM=BN=128, BK=32, 256 threads, 8x8 micro-tile per thread.
// ---------------------------------------------------------------------------
template<bool RELU>
__global__ __launch_bounds__(256)
void gemm_bias_kernel(const float* __restrict__ A, const float* __restrict__ B,
                      const float* __restrict__ bias, float* __restrict__ C,
                      int M, int N, int K) {
  constexpr int BM = 128, BK = 32, LS = BM + 4;
  __shared__ float As[BK * LS];
  __shared__ float Bs[BK * LS];
  const int tid = threadIdx.x;
  const int tn = tid & 15, tm = tid >> 4;
  const long m0 = (long)blockIdx.y * BM;
  const long n0 = (long)blockIdx.x * BM;
  const int srow = tid >> 3;        // 0..31
  const int skq  = (tid & 7) * 4;   // 0..28
  const float* Ab = A + m0 * K;
  const float* Bb = B + n0 * K;

  float4 pa[4], pb[4];
#pragma unroll
  for (int p = 0; p < 4; p++){
    pa[p] = *(const float4*)(Ab + (long)(p*32 + srow)*K + skq);
    pb[p] = *(const float4*)(Bb + (long)(p*32 + srow)*K + skq);
  }

  float acc[8][8];
#pragma unroll
  for (int i = 0; i < 8; i++)
#pragma unroll
    for (int j = 0; j < 8; j++) acc[i][j] = 0.f;

  const int nt = K / BK;
  for (int t = 0; t < nt; t++){
    __syncthreads();
#pragma unroll
    for (int p = 0; p < 4; p++){
      int r = p*32 + srow;
      As[(skq+0)*LS + r] = pa[p].x;
      As[(skq+1)*LS + r] = pa[p].y;
      As[(skq+2)*LS + r] = pa[p].z;
      As[(skq+3)*LS + r] = pa[p].w;
      Bs[(skq+0)*LS + r] = pb[p].x;
      Bs[(skq+1)*LS + r] = pb[p].y;
      Bs[(skq+2)*LS + r] = pb[p].z;
      Bs[(skq+3)*LS + r] = pb[p].w;
    }
    __syncthreads();
    if (t + 1 < nt){
      const float* An = Ab + (t+1)*BK;
      const float* Bn = Bb + (t+1)*BK;
#pragma unroll
      for (int p = 0; p < 4; p++){
        pa[p] = *(const float4*)(An + (long)(p*32 + srow)*K + skq);
        pb[p] = *(const float4*)(Bn + (long)(p*32 + srow)*K + skq);
      }
    }
#pragma unroll 8
    for (int kk = 0; kk < BK; kk++){
      float a[8], b[8];
      *(float4*)&a[0] = *(const float4*)&As[kk*LS + tm*8];
      *(float4*)&a[4] = *(const float4*)&As[kk*LS + tm*8 + 4];
      *(float4*)&b[0] = *(const float4*)&Bs[kk*LS + tn*8];
      *(float4*)&b[4] = *(const float4*)&Bs[kk*LS + tn*8 + 4];
#pragma unroll
      for (int i = 0; i < 8; i++)
#pragma unroll
        for (int j = 0; j < 8; j++)
          acc[i][j] = fmaf(a[i], b[j], acc[i][j]);
    }
  }

  float bv[8];
#pragma unroll
  for (int j = 0; j < 8; j++) bv[j] = bias[n0 + tn*8 + j];
#pragma unroll
  for (int i = 0; i < 8; i++){
    float o[8];
#pragma unroll
    for (int j = 0; j < 8; j++){
      float v = acc[i][j] + bv[j];
      o[j] = RELU ? fmaxf(v, 0.f) : v;
    }
    float* Cp = C + (m0 + tm*8 + i)*N + n0 + tn*8;
    *(float4*)&Cp[0] = *(const float4*)&o[0];
    *(float4*)&Cp[4] = *(const float4*)&o[4];
  }
}

// ---------------------------------------------------------------------------
// Fused residual-VQ (see round-0 notes). Unchanged.
// ---------------------------------------------------------------------------
__global__ __launch_bounds__(256)
void vq_kernel(const float* __restrict__ z,
               const float* __restrict__ E0c, const float* __restrict__ E1c,
               const float* __restrict__ E2c,
               float* __restrict__ qout, float* __restrict__ out,
               float* __restrict__ partial) {
  constexpr int VS = 132;
  __shared__ float rs[64 * VS];
  __shared__ float Es[64 * VS];
  __shared__ float pE[4 * 64];
  __shared__ float redv[64 * 16];
  __shared__ int   redi[64 * 16];
  __shared__ int   besti[3 * 64];
  __shared__ float wsum[4];

  const int tid  = threadIdx.x;
  const int row0 = blockIdx.x * 64;
  const int tn = tid & 15, tm = tid >> 4;
  const int urow = tid & 63, uq = tid >> 6;

#pragma unroll
  for (int i = 0; i < 8; i++){
    int idx = i*256 + tid;
    int r = idx >> 5, c = (idx & 31) * 4;
    *(float4*)&rs[r*VS + c] = *(const float4*)&z[(long)(row0 + r)*D_EMB + c];
  }

  float4 qa[8];
#pragma unroll
  for (int j = 0; j < 8; j++) qa[j] = make_float4(0.f, 0.f, 0.f, 0.f);
  float lsum = 0.f;

  const float* Etab[3] = {E0c, E1c, E2c};
  const int    Ktab[3] = {8, 64, 512};

  for (int l = 0; l < 3; l++){
    const float* E = Etab[l];
    const int K = Ktab[l];
    float bd[4]; int bi[4];
#pragma unroll
    for (int i = 0; i < 4; i++){ bd[i] = 3.0e38f; bi[i] = 0x7fffffff; }

    for (int kbase = 0; kbase < K; kbase += 64){
      const int cn = (K - kbase < 64) ? (K - kbase) : 64;
      __syncthreads();
#pragma unroll
      for (int i = 0; i < 8; i++){
        int idx = i*256 + tid;
        if (idx < cn*32){
          int r = idx >> 5, c = (idx & 31) * 4;
          *(float4*)&Es[r*VS + c] = *(const float4*)&E[(long)(kbase + r)*D_EMB + c];
        }
      }
      __syncthreads();
      {
        int c = tid & 63, qq = tid >> 6;
        float s = 0.f;
        if (c < cn){
#pragma unroll
          for (int j = 0; j < 8; j++){
            float4 v = *(const float4*)&Es[c*VS + qq*32 + j*4];
            s += dot4(v, v);
          }
        }
        pE[qq*64 + c] = s;
      }
      __syncthreads();
      float acc[4][4];
#pragma unroll
      for (int i = 0; i < 4; i++)
#pragma unroll
        for (int j = 0; j < 4; j++) acc[i][j] = 0.f;
      for (int d4 = 0; d4 < 32; d4++){
        float4 rv[4], ev[4];
#pragma unroll
        for (int i = 0; i < 4; i++) rv[i] = *(const float4*)&rs[(tm + 16*i)*VS + d4*4];
#pragma unroll
        for (int j = 0; j < 4; j++) ev[j] = *(const float4*)&Es[(tn + 16*j)*VS + d4*4];
#pragma unroll
        for (int i = 0; i < 4; i++)
#pragma unroll
          for (int j = 0; j < 4; j++)
            acc[i][j] = fmaf(rv[i].x, ev[j].x, fmaf(rv[i].y, ev[j].y,
                         fmaf(rv[i].z, ev[j].z, fmaf(rv[i].w, ev[j].w, acc[i][j]))));
      }
#pragma unroll
      for (int j = 0; j < 4; j++){
        int k = tn + 16*j;
        if (k < cn){
          float ne = pE[k] + pE[64+k] + pE[128+k] + pE[192+k];
          int kg = kbase + k;
#pragma unroll
          for (int i = 0; i < 4; i++){
            float sd = fmaf(-2.f, acc[i][j], ne);
            if (sd < bd[i] || (sd == bd[i] && kg < bi[i])){ bd[i] = sd; bi[i] = kg; }
          }
        }
      }
    }
#pragma unroll
    for (int i = 0; i < 4; i++){
      redv[(tm + 16*i)*16 + tn] = bd[i];
      redi[(tm + 16*i)*16 + tn] = bi[i];
    }
    __syncthreads();
    if (tid < 64){
      float best = 3.9e38f; int bk = 0x7fffffff;
      for (int t = 0; t < 16; t++){
        float v = redv[tid*16 + t]; int k = redi[tid*16 + t];
        if (v < best || (v == best && k < bk)){ best = v; bk = k; }
      }
      besti[l*64 + tid] = bk;
    }
    __syncthreads();
    {
      int k = besti[l*64 + urow];
      const float* Er = E + (long)k*D_EMB + uq*32;
#pragma unroll
      for (int j = 0; j < 8; j++){
        float4 e = *(const float4*)&Er[j*4];
        float* rp = &rs[urow*VS + uq*32 + j*4];
        float4 r = *(const float4*)rp;
        float4 df = make_float4(e.x-r.x, e.y-r.y, e.z-r.z, e.w-r.w);
        lsum += dot4(df, df);
        *(float4*)rp = make_float4(r.x-e.x, r.y-e.y, r.z-e.z, r.w-e.w);
        qa[j].x += e.x; qa[j].y += e.y; qa[j].z += e.z; qa[j].w += e.w;
      }
    }
  }

  __syncthreads();
#pragma unroll
  for (int j = 0; j < 8; j++)
    *(float4*)&Es[urow*VS + uq*32 + j*4] = qa[j];
  __syncthreads();
#pragma unroll
  for (int i = 0; i < 8; i++){
    int idx = i*256 + tid;
    int r = idx >> 5, c = (idx & 31) * 4;
    *(float4*)&qout[(long)(row0 + r)*D_EMB + c] = *(const float4*)&Es[r*VS + c];
  }
  if (tid < 64){
    long n = row0 + tid;
    for (int l = 0; l < 3; l++)
      out[CODES_OFF + n*3 + l] = (float)besti[l*64 + tid];
  }
  for (int off = 32; off > 0; off >>= 1) lsum += __shfl_down(lsum, off);
  if ((tid & 63) == 0) wsum[tid >> 6] = lsum;
  __syncthreads();
  if (tid == 0) partial[blockIdx.x] = wsum[0] + wsum[1] + wsum[2] + wsum[3];
}

__global__ __launch_bounds__(256)
void loss_reduce_kernel(const float* __restrict__ partial, float* __restrict__ out){
  __shared__ float ws2[4];
  int tid = threadIdx.x;
  float s = 0.f;
  for (int i = tid; i < 1024; i += 256) s += partial[i];
  for (int off = 32; off > 0; off >>= 1) s += __shfl_down(s, off);
  if ((tid & 63) == 0) ws2[tid >> 6] = s;
  __syncthreads();
  if (tid == 0)
    out[LOSS_OFF] = (ws2[0] + ws2[1] + ws2[2] + ws2[3]) * (0.25f / (float)((long)NROWS * D_EMB));
}

extern "C" void kernel_launch(void* const* d_in, const int* in_sizes, int n_in,
                              void* d_out, int out_size, void* d_ws, size_t ws_size,
                              hipStream_t stream) {
  (void)in_sizes; (void)n_in; (void)out_size; (void)ws_size;
  const float* x   = (const float*)d_in[0];
  const float* We1 = (const float*)d_in[1];
  const float* be1 = (const float*)d_in[2];
  const float* We2 = (const float*)d_in[3];
  const float* be2 = (const float*)d_in[4];
  const float* Wd1 = (const float*)d_in[5];
  const float* bd1 = (const float*)d_in[6];
  const float* Wd2 = (const float*)d_in[7];
  const float* bd2 = (const float*)d_in[8];
  const float* E0  = (const float*)d_in[9];
  const float* E1  = (const float*)d_in[10];
  const float* E2  = (const float*)d_in[11];
  float* out = (float*)d_out;
  char*  ws  = (char*)d_ws;

  // Workspace layout — total use 224 MiB (round-2 bug: previous layout wrote
  // `partial` at ws+256MiB, exactly past a likely 256 MiB ws_size -> OOB
  // device writes -> replay corruption).
  //   h       : ws + 0        .. 201326592   (65536x768 f32; dead after GEMM2)
  //   h2      : ws + 0        .. 33554432    (reuse of dead h, GEMM3/4)
  //   q       : ws + 100663296.. 134217728   (inside dead-h, disjoint from h2)
  //   partial : ws + 150994944.. +4096       (inside dead-h, disjoint)
  //   z       : ws + 201326592.. 234881024   (live with h during GEMM2)
  float* h       = (float*)ws;
  float* h2      = (float*)ws;
  float* q       = (float*)(ws + 100663296L);
  float* partial = (float*)(ws + 150994944L);
  float* z       = (float*)(ws + 201326592L);

  dim3 blk(256);
  gemm_bias_kernel<true ><<<dim3(D_IN/128,  NROWS/128), blk, 0, stream>>>(x,  We1, be1, h,  NROWS, D_IN,  D_IN);
  gemm_bias_kernel<false><<<dim3(D_EMB/128, NROWS/128), blk, 0, stream>>>(h,  We2, be2, z,  NROWS, D_EMB, D_IN);
  vq_kernel<<<dim3(NROWS/64), blk, 0, stream>>>(z, E0, E1, E2, q, out, partial);
  loss_reduce_kernel<<<dim3(1), blk, 0, stream>>>(partial, out);
  gemm_bias_kernel<true ><<<dim3(1, NROWS/128), blk, 0, stream>>>(q,  Wd1, bd1, h2, NROWS, D_EMB, D_EMB);
  gemm_bias_kernel<false><<<dim3(1, NROWS/128), blk, 0, stream>>>(h2, Wd2, bd2, out, NROWS, D_EMB, D_EMB);
}

// Round 6
// 621.970 us; speedup vs baseline: 2.3507x; 2.3507x over previous
//
#include <hip/hip_runtime.h>

typedef _Float16 f16;
typedef __attribute__((ext_vector_type(4))) _Float16 f16x4;
typedef __attribute__((ext_vector_type(8))) _Float16 f16x8;
typedef __attribute__((ext_vector_type(4))) float    f32x4;

static constexpr int NROWS = 65536;
static constexpr int D_IN  = 768;
static constexpr int D_EMB = 128;
static constexpr long LOSS_OFF  = (long)NROWS * D_EMB;   // 8388608
static constexpr long CODES_OFF = LOSS_OFF + 1;

__device__ __forceinline__ float dot4(float4 a, float4 b){
  return fmaf(a.x,b.x, fmaf(a.y,b.y, fmaf(a.z,b.z, a.w*b.w)));
}

// Split fp32 -> fp16 hi + fp16 lo*2^-11. lo is pre-scaled by 2048 so it stays
// in fp16 normal range (no subnormal/FTZ hazard). a ~= hi + lo/2048 to 2^-22.
__device__ __forceinline__ void split4(float4 v, f16x4& hi, f16x4& lo){
  float a0=v.x, a1=v.y, a2=v.z, a3=v.w;
  _Float16 h0=(_Float16)a0, h1=(_Float16)a1, h2=(_Float16)a2, h3=(_Float16)a3;
  hi[0]=h0; hi[1]=h1; hi[2]=h2; hi[3]=h3;
  lo[0]=(_Float16)((a0-(float)h0)*2048.0f);
  lo[1]=(_Float16)((a1-(float)h1)*2048.0f);
  lo[2]=(_Float16)((a2-(float)h2)*2048.0f);
  lo[3]=(_Float16)((a3-(float)h3)*2048.0f);
}

// ---------------------------------------------------------------------------
// MFMA GEMM via fp16 two-plane split: C = A[M,K] * B[N,K]^T + bias (opt relu).
// Error class == fp32 GEMM (dropped term 2^-22 per product < fp32 accum noise).
// BM=BN=128, BK=32, 4 waves; wave -> 64x64 quadrant; 4x4 frags of 16x16x32.
// acc_main = hi*hi; acc_corr = hi*lo + lo*hi; C = main + corr/2048 + bias.
// LDS: 4 planes 128x32 f16, row stride 40 halves (frag reads at bank floor).
// ---------------------------------------------------------------------------
template<bool RELU>
__global__ __launch_bounds__(256, 2)
void gemm_mfma_kernel(const float* __restrict__ A, const float* __restrict__ B,
                      const float* __restrict__ bias, float* __restrict__ C,
                      int M, int N, int K) {
  constexpr int RS = 40;   // LDS row stride (halves)
  __shared__ f16 Ah[128*RS];
  __shared__ f16 Al[128*RS];
  __shared__ f16 Bhs[128*RS];
  __shared__ f16 Bls[128*RS];

  const int tid  = threadIdx.x;
  const int wave = tid >> 6, lane = tid & 63;
  const int wm = wave >> 1, wn = wave & 1;
  const int lr = lane & 15, lg = lane >> 4;
  const long m0 = (long)blockIdx.y * 128;
  const long n0 = (long)blockIdx.x * 128;
  const float* Ab = A + m0 * K;
  const float* Bb = B + n0 * K;
  const int srow = tid >> 3;   // 0..31
  const int sc4  = tid & 7;    // float4 column 0..7

  float4 pa[4], pb[4];
#pragma unroll
  for (int p = 0; p < 4; p++){
    pa[p] = *(const float4*)(Ab + (long)(p*32 + srow)*K + sc4*4);
    pb[p] = *(const float4*)(Bb + (long)(p*32 + srow)*K + sc4*4);
  }

  f32x4 accm[4][4], accc[4][4];
#pragma unroll
  for (int i = 0; i < 4; i++)
#pragma unroll
    for (int j = 0; j < 4; j++){
      accm[i][j] = (f32x4){0.f,0.f,0.f,0.f};
      accc[i][j] = (f32x4){0.f,0.f,0.f,0.f};
    }

  const int nt = K / 32;
  for (int t = 0; t < nt; t++){
    __syncthreads();
#pragma unroll
    for (int p = 0; p < 4; p++){
      int r = p*32 + srow;
      f16x4 h4, l4;
      split4(pa[p], h4, l4);
      *(f16x4*)&Ah[r*RS + sc4*4] = h4;
      *(f16x4*)&Al[r*RS + sc4*4] = l4;
      split4(pb[p], h4, l4);
      *(f16x4*)&Bhs[r*RS + sc4*4] = h4;
      *(f16x4*)&Bls[r*RS + sc4*4] = l4;
    }
    __syncthreads();
    if (t + 1 < nt){
      const float* An = Ab + (t+1)*32;
      const float* Bn = Bb + (t+1)*32;
#pragma unroll
      for (int p = 0; p < 4; p++){
        pa[p] = *(const float4*)(An + (long)(p*32 + srow)*K + sc4*4);
        pb[p] = *(const float4*)(Bn + (long)(p*32 + srow)*K + sc4*4);
      }
    }
    f16x8 ah[4], al[4];
#pragma unroll
    for (int mi = 0; mi < 4; mi++){
      int row = wm*64 + mi*16 + lr;
      ah[mi] = *(const f16x8*)&Ah[row*RS + lg*8];
      al[mi] = *(const f16x8*)&Al[row*RS + lg*8];
    }
#pragma unroll
    for (int ni = 0; ni < 4; ni++){
      int col = wn*64 + ni*16 + lr;
      f16x8 bh = *(const f16x8*)&Bhs[col*RS + lg*8];
      f16x8 bl = *(const f16x8*)&Bls[col*RS + lg*8];
#pragma unroll
      for (int mi = 0; mi < 4; mi++){
        accm[mi][ni] = __builtin_amdgcn_mfma_f32_16x16x32_f16(ah[mi], bh, accm[mi][ni], 0, 0, 0);
        accc[mi][ni] = __builtin_amdgcn_mfma_f32_16x16x32_f16(ah[mi], bl, accc[mi][ni], 0, 0, 0);
        accc[mi][ni] = __builtin_amdgcn_mfma_f32_16x16x32_f16(al[mi], bh, accc[mi][ni], 0, 0, 0);
      }
    }
  }

  float bv[4];
#pragma unroll
  for (int ni = 0; ni < 4; ni++) bv[ni] = bias[n0 + wn*64 + ni*16 + lr];
#pragma unroll
  for (int mi = 0; mi < 4; mi++){
#pragma unroll
    for (int ni = 0; ni < 4; ni++){
#pragma unroll
      for (int r = 0; r < 4; r++){
        float v = accm[mi][ni][r] + accc[mi][ni][r]*(1.0f/2048.0f) + bv[ni];
        if (RELU) v = fmaxf(v, 0.f);
        long row = m0 + wm*64 + mi*16 + lg*4 + r;
        C[row*N + n0 + wn*64 + ni*16 + lr] = v;
      }
    }
  }
}

// ---------------------------------------------------------------------------
// Fused residual-VQ (unchanged from validated baseline).
// ---------------------------------------------------------------------------
__global__ __launch_bounds__(256)
void vq_kernel(const float* __restrict__ z,
               const float* __restrict__ E0c, const float* __restrict__ E1c,
               const float* __restrict__ E2c,
               float* __restrict__ qout, float* __restrict__ out,
               float* __restrict__ partial) {
  constexpr int VS = 132;
  __shared__ float rs[64 * VS];
  __shared__ float Es[64 * VS];
  __shared__ float pE[4 * 64];
  __shared__ float redv[64 * 16];
  __shared__ int   redi[64 * 16];
  __shared__ int   besti[3 * 64];
  __shared__ float wsum[4];

  const int tid  = threadIdx.x;
  const int row0 = blockIdx.x * 64;
  const int tn = tid & 15, tm = tid >> 4;
  const int urow = tid & 63, uq = tid >> 6;

#pragma unroll
  for (int i = 0; i < 8; i++){
    int idx = i*256 + tid;
    int r = idx >> 5, c = (idx & 31) * 4;
    *(float4*)&rs[r*VS + c] = *(const float4*)&z[(long)(row0 + r)*D_EMB + c];
  }

  float4 qa[8];
#pragma unroll
  for (int j = 0; j < 8; j++) qa[j] = make_float4(0.f, 0.f, 0.f, 0.f);
  float lsum = 0.f;

  const float* Etab[3] = {E0c, E1c, E2c};
  const int    Ktab[3] = {8, 64, 512};

  for (int l = 0; l < 3; l++){
    const float* E = Etab[l];
    const int K = Ktab[l];
    float bd[4]; int bi[4];
#pragma unroll
    for (int i = 0; i < 4; i++){ bd[i] = 3.0e38f; bi[i] = 0x7fffffff; }

    for (int kbase = 0; kbase < K; kbase += 64){
      const int cn = (K - kbase < 64) ? (K - kbase) : 64;
      __syncthreads();
#pragma unroll
      for (int i = 0; i < 8; i++){
        int idx = i*256 + tid;
        if (idx < cn*32){
          int r = idx >> 5, c = (idx & 31) * 4;
          *(float4*)&Es[r*VS + c] = *(const float4*)&E[(long)(kbase + r)*D_EMB + c];
        }
      }
      __syncthreads();
      {
        int c = tid & 63, qq = tid >> 6;
        float s = 0.f;
        if (c < cn){
#pragma unroll
          for (int j = 0; j < 8; j++){
            float4 v = *(const float4*)&Es[c*VS + qq*32 + j*4];
            s += dot4(v, v);
          }
        }
        pE[qq*64 + c] = s;
      }
      __syncthreads();
      float acc[4][4];
#pragma unroll
      for (int i = 0; i < 4; i++)
#pragma unroll
        for (int j = 0; j < 4; j++) acc[i][j] = 0.f;
      for (int d4 = 0; d4 < 32; d4++){
        float4 rv[4], ev[4];
#pragma unroll
        for (int i = 0; i < 4; i++) rv[i] = *(const float4*)&rs[(tm + 16*i)*VS + d4*4];
#pragma unroll
        for (int j = 0; j < 4; j++) ev[j] = *(const float4*)&Es[(tn + 16*j)*VS + d4*4];
#pragma unroll
        for (int i = 0; i < 4; i++)
#pragma unroll
          for (int j = 0; j < 4; j++)
            acc[i][j] = fmaf(rv[i].x, ev[j].x, fmaf(rv[i].y, ev[j].y,
                         fmaf(rv[i].z, ev[j].z, fmaf(rv[i].w, ev[j].w, acc[i][j]))));
      }
#pragma unroll
      for (int j = 0; j < 4; j++){
        int k = tn + 16*j;
        if (k < cn){
          float ne = pE[k] + pE[64+k] + pE[128+k] + pE[192+k];
          int kg = kbase + k;
#pragma unroll
          for (int i = 0; i < 4; i++){
            float sd = fmaf(-2.f, acc[i][j], ne);
            if (sd < bd[i] || (sd == bd[i] && kg < bi[i])){ bd[i] = sd; bi[i] = kg; }
          }
        }
      }
    }
#pragma unroll
    for (int i = 0; i < 4; i++){
      redv[(tm + 16*i)*16 + tn] = bd[i];
      redi[(tm + 16*i)*16 + tn] = bi[i];
    }
    __syncthreads();
    if (tid < 64){
      float best = 3.9e38f; int bk = 0x7fffffff;
      for (int t = 0; t < 16; t++){
        float v = redv[tid*16 + t]; int k = redi[tid*16 + t];
        if (v < best || (v == best && k < bk)){ best = v; bk = k; }
      }
      besti[l*64 + tid] = bk;
    }
    __syncthreads();
    {
      int k = besti[l*64 + urow];
      const float* Er = E + (long)k*D_EMB + uq*32;
#pragma unroll
      for (int j = 0; j < 8; j++){
        float4 e = *(const float4*)&Er[j*4];
        float* rp = &rs[urow*VS + uq*32 + j*4];
        float4 r = *(const float4*)rp;
        float4 df = make_float4(e.x-r.x, e.y-r.y, e.z-r.z, e.w-r.w);
        lsum += dot4(df, df);
        *(float4*)rp = make_float4(r.x-e.x, r.y-e.y, r.z-e.z, r.w-e.w);
        qa[j].x += e.x; qa[j].y += e.y; qa[j].z += e.z; qa[j].w += e.w;
      }
    }
  }

  __syncthreads();
#pragma unroll
  for (int j = 0; j < 8; j++)
    *(float4*)&Es[urow*VS + uq*32 + j*4] = qa[j];
  __syncthreads();
#pragma unroll
  for (int i = 0; i < 8; i++){
    int idx = i*256 + tid;
    int r = idx >> 5, c = (idx & 31) * 4;
    *(float4*)&qout[(long)(row0 + r)*D_EMB + c] = *(const float4*)&Es[r*VS + c];
  }
  if (tid < 64){
    long n = row0 + tid;
    for (int l = 0; l < 3; l++)
      out[CODES_OFF + n*3 + l] = (float)besti[l*64 + tid];
  }
  for (int off = 32; off > 0; off >>= 1) lsum += __shfl_down(lsum, off);
  if ((tid & 63) == 0) wsum[tid >> 6] = lsum;
  __syncthreads();
  if (tid == 0) partial[blockIdx.x] = wsum[0] + wsum[1] + wsum[2] + wsum[3];
}

__global__ __launch_bounds__(256)
void loss_reduce_kernel(const float* __restrict__ partial, float* __restrict__ out){
  __shared__ float ws2[4];
  int tid = threadIdx.x;
  float s = 0.f;
  for (int i = tid; i < 1024; i += 256) s += partial[i];
  for (int off = 32; off > 0; off >>= 1) s += __shfl_down(s, off);
  if ((tid & 63) == 0) ws2[tid >> 6] = s;
  __syncthreads();
  if (tid == 0)
    out[LOSS_OFF] = (ws2[0] + ws2[1] + ws2[2] + ws2[3]) * (0.25f / (float)((long)NROWS * D_EMB));
}

extern "C" void kernel_launch(void* const* d_in, const int* in_sizes, int n_in,
                              void* d_out, int out_size, void* d_ws, size_t ws_size,
                              hipStream_t stream) {
  (void)in_sizes; (void)n_in; (void)out_size; (void)ws_size;
  const float* x   = (const float*)d_in[0];
  const float* We1 = (const float*)d_in[1];
  const float* be1 = (const float*)d_in[2];
  const float* We2 = (const float*)d_in[3];
  const float* be2 = (const float*)d_in[4];
  const float* Wd1 = (const float*)d_in[5];
  const float* bd1 = (const float*)d_in[6];
  const float* Wd2 = (const float*)d_in[7];
  const float* bd2 = (const float*)d_in[8];
  const float* E0  = (const float*)d_in[9];
  const float* E1  = (const float*)d_in[10];
  const float* E2  = (const float*)d_in[11];
  float* out = (float*)d_out;
  char*  ws  = (char*)d_ws;

  // Workspace layout — max use 224 MiB (validated round 5).
  float* h       = (float*)ws;                    // 65536x768, dead after GEMM2
  float* h2      = (float*)ws;                    // reuse of dead h
  float* q       = (float*)(ws + 100663296L);     // inside dead-h, disjoint from h2
  float* partial = (float*)(ws + 150994944L);     // inside dead-h, disjoint
  float* z       = (float*)(ws + 201326592L);     // live with h during GEMM2

  dim3 blk(256);
  gemm_mfma_kernel<true ><<<dim3(D_IN/128,  NROWS/128), blk, 0, stream>>>(x,  We1, be1, h,  NROWS, D_IN,  D_IN);
  gemm_mfma_kernel<false><<<dim3(D_EMB/128, NROWS/128), blk, 0, stream>>>(h,  We2, be2, z,  NROWS, D_EMB, D_IN);
  vq_kernel<<<dim3(NROWS/64), blk, 0, stream>>>(z, E0, E1, E2, q, out, partial);
  loss_reduce_kernel<<<dim3(1), blk, 0, stream>>>(partial, out);
  gemm_mfma_kernel<true ><<<dim3(D_EMB/128, NROWS/128), blk, 0, stream>>>(q,  Wd1, bd1, h2, NROWS, D_EMB, D_EMB);
  gemm_mfma_kernel<false><<<dim3(D_EMB/128, NROWS/128), blk, 0, stream>>>(h2, Wd2, bd2, out, NROWS, D_EMB, D_EMB);
}